// Round 7
// baseline (29988.663 us; speedup 1.0000x reference)
//
#include <hip/hip_runtime.h>
#include <hip/hip_fp16.h>

typedef _Float16 f16;
typedef __attribute__((ext_vector_type(8))) _Float16 f16x8;
typedef __attribute__((ext_vector_type(16))) float f32x16;

#define NB 2048      // batch
#define SEQ 64       // warmup sequence length
#define NF 3         // features
#define NU 512       // units
#define N4U 2048     // 4*units
#define NSTEP 127    // 64 warmup + 63 rollout
#define ROWS 32      // batch rows per block (fully independent rows!)
#define NBLK 64      // 64 blocks x 32 rows = 2048
#define H_LD 520     // h LDS row stride in f16 (65 16B-granules, odd -> conflict-free b128)

// Wp fragment-ordered W^T: [nt 0..63][kt 0..31][lane 0..63][8 f16]
//   Wp[nt][kt][l][j] = rec[kt*16 + (l>>5)*8 + j][nt*32 + (l&31)]
// Each wave-load of a B fragment is 64 lanes x 16 B fully coalesced.
__global__ void wt_pack_kernel(const float* __restrict__ rec, f16* __restrict__ Wp) {
    const int g  = blockIdx.x * blockDim.x + threadIdx.x;   // 0..131071
    const int l  = g & 63;
    const int kt = (g >> 6) & 31;
    const int nt = g >> 11;
    const int n  = nt * 32 + (l & 31);
    const int k0 = kt * 16 + (l >> 5) * 8;
    f16x8 v;
    #pragma unroll
    for (int j = 0; j < 8; ++j) v[j] = (f16)rec[(size_t)(k0 + j) * N4U + n];
    *(f16x8*)(Wp + (size_t)g * 8) = v;
}

__device__ __forceinline__ float fast_rcp(float x) { return __builtin_amdgcn_rcpf(x); }
__device__ __forceinline__ float sigf(float x) { return fast_rcp(1.f + __expf(-x)); }
__device__ __forceinline__ float tanhf_fast(float x) {
    float a = fabsf(x);
    float e = __expf(-2.f * a);
    float t = (1.f - e) * fast_rcp(1.f + e);
    return copysignf(t, x);
}

__global__ __launch_bounds__(256, 1)
void lstm_rowlocal_kernel(const float* __restrict__ inputs, const float* __restrict__ kernw,
                          const float* __restrict__ bias, const float* __restrict__ dw,
                          const float* __restrict__ db, float* __restrict__ out,
                          const f16* __restrict__ Wp)
{
    __shared__ f16   h_lds[ROWS * H_LD];     // block-local h state, fp16 (as baseline)
    __shared__ float x_s[ROWS * 3];          // per-row x (fp32 path, as baseline)
    __shared__ float predp[4][ROWS][3];      // per-wave pred partials

    const int tid = threadIdx.x;
    const int w = tid >> 6, l = tid & 63, l31 = l & 31, hf = l >> 5;
    const int bBase = blockIdx.x * ROWS;

    // per-lane constants: this lane covers u = w*128 + nl*32 + l31, nl = 0..3
    float kr[4][4][3], br[4][4], dwr[4][3], dbr[3];
    #pragma unroll
    for (int nl = 0; nl < 4; ++nl) {
        const int u = w * 128 + nl * 32 + l31;
        #pragma unroll
        for (int g = 0; g < 4; ++g) {
            const int gc = g * NU + u;
            #pragma unroll
            for (int f = 0; f < 3; ++f) kr[nl][g][f] = kernw[f * N4U + gc];
            br[nl][g] = bias[gc];
        }
        #pragma unroll
        for (int j = 0; j < 3; ++j) dwr[nl][j] = dw[u * 3 + j];
    }
    #pragma unroll
    for (int j = 0; j < 3; ++j) dbr[j] = db[j];

    float c_reg[4][16];
    #pragma unroll
    for (int nl = 0; nl < 4; ++nl)
        #pragma unroll
        for (int r = 0; r < 16; ++r) c_reg[nl][r] = 0.f;

    for (int s = 0; s < NSTEP; ++s) {
        // ---- stage x for warmup (rollout x_s was written by last iter's combine)
        if (s < SEQ && tid < ROWS) {
            const float* xp = inputs + ((size_t)(bBase + tid) * SEQ + s) * NF;
            x_s[tid * 3 + 0] = xp[0];
            x_s[tid * 3 + 1] = xp[1];
            x_s[tid * 3 + 2] = xp[2];
        }
        __syncthreads();   // x_s ready; prev-iter h_lds writes visible

        // ---- A fragments: lane holds h[m=l31][k = kt*16 + hf*8 + j] (baseline mapping)
        f16x8 areg[32];
        if (s > 0) {
            #pragma unroll
            for (int kt = 0; kt < 32; ++kt)
                areg[kt] = *(const f16x8*)(h_lds + l31 * H_LD + kt * 16 + hf * 8);
        }
        __syncthreads();   // all waves done reading h_lds -> safe to overwrite below

        const int n_out = s - (SEQ - 1);
        float v[16][3];    // pred partials over this wave's 128 u
        #pragma unroll
        for (int r = 0; r < 16; ++r) { v[r][0] = 0.f; v[r][1] = 0.f; v[r][2] = 0.f; }

        const f16* wlane = Wp + (size_t)l * 8;
        #pragma unroll
        for (int nl = 0; nl < 4; ++nl) {
            f32x16 a0 = {}, a1 = {}, a2 = {}, a3 = {};
            if (s > 0) {
                const int ntb = w * 4 + nl;                 // u-chunk tile index within a gate
                const f16* w0 = wlane + (size_t)((0 * 16 + ntb) * 32) * 512;
                const f16* w1 = wlane + (size_t)((1 * 16 + ntb) * 32) * 512;
                const f16* w2 = wlane + (size_t)((2 * 16 + ntb) * 32) * 512;
                const f16* w3 = wlane + (size_t)((3 * 16 + ntb) * 32) * 512;
                #pragma unroll
                for (int kt = 0; kt < 32; ++kt) {           // 4 independent acc chains
                    f16x8 b0 = *(const f16x8*)(w0 + kt * 512);
                    f16x8 b1 = *(const f16x8*)(w1 + kt * 512);
                    f16x8 b2 = *(const f16x8*)(w2 + kt * 512);
                    f16x8 b3 = *(const f16x8*)(w3 + kt * 512);
                    a0 = __builtin_amdgcn_mfma_f32_32x32x16_f16(areg[kt], b0, a0, 0, 0, 0);
                    a1 = __builtin_amdgcn_mfma_f32_32x32x16_f16(areg[kt], b1, a1, 0, 0, 0);
                    a2 = __builtin_amdgcn_mfma_f32_32x32x16_f16(areg[kt], b2, a2, 0, 0, 0);
                    a3 = __builtin_amdgcn_mfma_f32_32x32x16_f16(areg[kt], b3, a3, 0, 0, 0);
                }
            }
            // ---- gates + state update (fp32 x-path identical to baseline numerics)
            const int ucol = w * 128 + nl * 32 + l31;
            #pragma unroll
            for (int r = 0; r < 16; ++r) {
                const int row = (r & 3) + ((r >> 2) << 3) + (hf << 2);  // C-layout row
                const float x0 = x_s[row * 3 + 0];
                const float x1 = x_s[row * 3 + 1];
                const float x2 = x_s[row * 3 + 2];
                float z0 = a0[r] + x0 * kr[nl][0][0] + x1 * kr[nl][0][1] + x2 * kr[nl][0][2] + br[nl][0];
                float z1 = a1[r] + x0 * kr[nl][1][0] + x1 * kr[nl][1][1] + x2 * kr[nl][1][2] + br[nl][1];
                float z2 = a2[r] + x0 * kr[nl][2][0] + x1 * kr[nl][2][1] + x2 * kr[nl][2][2] + br[nl][2];
                float z3 = a3[r] + x0 * kr[nl][3][0] + x1 * kr[nl][3][1] + x2 * kr[nl][3][2] + br[nl][3];
                const float gi = sigf(z0);
                const float gf = sigf(z1);
                const float gg = tanhf_fast(z2);
                const float go = sigf(z3);
                const float cv = gf * c_reg[nl][r] + gi * gg;
                c_reg[nl][r] = cv;
                const float h2 = go * tanhf_fast(cv);
                h_lds[row * H_LD + ucol] = (f16)h2;         // next step's A operand
                v[r][0] += h2 * dwr[nl][0];                 // pred partial from fp32 h2
                v[r][1] += h2 * dwr[nl][1];
                v[r][2] += h2 * dwr[nl][2];
            }
        }

        // ---- pred reduce: butterfly over 32 lanes (u within wave), then LDS
        if (n_out >= 0) {
            #pragma unroll
            for (int r = 0; r < 16; ++r) {
                #pragma unroll
                for (int j = 0; j < 3; ++j) {
                    float t = v[r][j];
                    t += __shfl_xor(t, 1, 64);
                    t += __shfl_xor(t, 2, 64);
                    t += __shfl_xor(t, 4, 64);
                    t += __shfl_xor(t, 8, 64);
                    t += __shfl_xor(t, 16, 64);
                    v[r][j] = t;
                }
                if (l31 == r) {
                    const int row = (r & 3) + ((r >> 2) << 3) + (hf << 2);
                    predp[w][row][0] = v[r][0];
                    predp[w][row][1] = v[r][1];
                    predp[w][row][2] = v[r][2];
                }
            }
        }
        __syncthreads();   // h_lds complete for next iter; predp ready

        // ---- combine pred across the 4 waves; feed back as next x; write out
        if (n_out >= 0 && tid < ROWS) {
            float p0 = dbr[0] + predp[0][tid][0] + predp[1][tid][0] + predp[2][tid][0] + predp[3][tid][0];
            float p1 = dbr[1] + predp[0][tid][1] + predp[1][tid][1] + predp[2][tid][1] + predp[3][tid][1];
            float p2 = dbr[2] + predp[0][tid][2] + predp[1][tid][2] + predp[2][tid][2] + predp[3][tid][2];
            float* o = out + ((size_t)n_out * NB + bBase + tid) * 3;
            o[0] = p0; o[1] = p1; o[2] = p2;
            x_s[tid * 3 + 0] = p0;   // consumed after next iter's top barrier
            x_s[tid * 3 + 1] = p1;
            x_s[tid * 3 + 2] = p2;
        }
    }
}

extern "C" void kernel_launch(void* const* d_in, const int* in_sizes, int n_in,
                              void* d_out, int out_size, void* d_ws, size_t ws_size,
                              hipStream_t stream) {
    const float* inputs = (const float*)d_in[0];
    const float* kernw  = (const float*)d_in[1];
    const float* rec    = (const float*)d_in[2];
    const float* bias   = (const float*)d_in[3];
    const float* dw     = (const float*)d_in[4];
    const float* db     = (const float*)d_in[5];
    float* out = (float*)d_out;

    f16* Wp = (f16*)d_ws;   // 2 MB fragment-ordered W^T

    // Pack W once (stream-ordered before the main kernel), then run the
    // fully row-local recurrence: zero inter-block communication.
    hipLaunchKernelGGL(wt_pack_kernel, dim3(512), dim3(256), 0, stream, rec, Wp);
    hipLaunchKernelGGL(lstm_rowlocal_kernel, dim3(NBLK), dim3(256), 0, stream,
                       inputs, kernw, bias, dw, db, out, Wp);
}